// Round 3
// baseline (204.922 us; speedup 1.0000x reference)
//
#include <hip/hip_runtime.h>

typedef unsigned short u16;
typedef unsigned int u32;

#define D_MODEL 1024
#define N_HEADS 16
#define D_HEAD 64
#define WIN 256
#define SEQ 2048
#define BATCH 2
#define NROWS (BATCH*SEQ)          // 4096 token rows

typedef short frag_ab __attribute__((ext_vector_type(8)));   // 8 bf16 (4 VGPRs)
typedef float frag_cd __attribute__((ext_vector_type(4)));   // 4 fp32 (16x16 C/D)
typedef float f32x16 __attribute__((ext_vector_type(16)));   // 32x32 C/D
typedef u16 u16x8 __attribute__((ext_vector_type(8)));

__device__ __forceinline__ u16 f2bf(float f) {
    union { float f; u32 u; } x; x.f = f;
    u32 r = x.u + 0x7fffu + ((x.u >> 16) & 1u);   // RNE
    return (u16)(r >> 16);
}

__device__ __forceinline__ void load_lds16(const void* g, void* l) {
    __builtin_amdgcn_global_load_lds(
        (const __attribute__((address_space(1))) void*)g,
        (__attribute__((address_space(3))) void*)l, 16, 0, 0);
}

// Device-scope grid barrier (G16): monotonic counter, release/acquire at agent
// scope (emits L2 writeback / invalidate across XCDs). 1 block/CU (112 KB LDS)
// guarantees all 256 blocks co-resident -> no deadlock. Monotonic target means
// a rocprof replay with a stale counter falls through instead of hanging.
__device__ __forceinline__ void grid_sync(u32* cnt, u32 target) {
    __syncthreads();                          // all waves' mem ops drained (vm+lgkm)
    if (threadIdx.x == 0) {
        __hip_atomic_fetch_add(cnt, 1u, __ATOMIC_RELEASE, __HIP_MEMORY_SCOPE_AGENT);
        u32 v;
        do {
            __builtin_amdgcn_s_sleep(2);
            v = __hip_atomic_load(cnt, __ATOMIC_ACQUIRE, __HIP_MEMORY_SCOPE_AGENT);
        } while (v < target);
    }
    __syncthreads();
}

// ---------------- transpose-cast tile helper (caller supplies LDS) ----------------
__device__ __forceinline__ void transpose_tile(const float* __restrict__ W, u16* __restrict__ WT,
                                               int K, int N, int n0, int k0,
                                               int scale_rows, float scale, float (*tile)[33]) {
    int x = threadIdx.x & 31, y = threadIdx.x >> 5;   // 32 x 8
#pragma unroll
    for (int r = 0; r < 4; r++)
        tile[y + 8 * r][x] = W[(size_t)(k0 + y + 8 * r) * N + n0 + x];
    __syncthreads();
#pragma unroll
    for (int r = 0; r < 4; r++) {
        int nrow = n0 + y + 8 * r;
        float v = tile[x][y + 8 * r];
        if (nrow < scale_rows) v *= scale;
        WT[(size_t)nrow * K + k0 + x] = f2bf(v);
    }
}

// ---------------- prep: cast x + transpose-cast W_qkv + W_out + zero sync counter ----------------
__global__ __launch_bounds__(256) void prep_kernel(const float* __restrict__ x,
                                                   const float* __restrict__ W_qkv,
                                                   const float* __restrict__ W_out,
                                                   u16* __restrict__ xb,
                                                   u16* __restrict__ wqkvT,
                                                   u16* __restrict__ woutT,
                                                   u32* __restrict__ sync_cnt,
                                                   float qscale) {
    __shared__ float tile[32][33];
    const int bid = blockIdx.x;
    if (bid == 0 && threadIdx.x == 0) *sync_cnt = 0;   // re-zero every iteration (ws is re-poisoned)
    if (bid < 4096) {
        int idx = bid * 256 + threadIdx.x;
        float4 v = ((const float4*)x)[idx];
        ushort4 o;
        o.x = f2bf(v.x); o.y = f2bf(v.y); o.z = f2bf(v.z); o.w = f2bf(v.w);
        ((ushort4*)xb)[idx] = o;
    } else if (bid < 7168) {
        int t = bid - 4096;                       // W_qkv: 96 x 32 tiles of 32x32
        transpose_tile(W_qkv, wqkvT, D_MODEL, 3 * D_MODEL, (t % 96) * 32, (t / 96) * 32,
                       D_MODEL, qscale, tile);
    } else {
        int t = bid - 7168;                       // W_out: 32 x 32 tiles
        transpose_tile(W_out, woutT, D_MODEL, D_MODEL, (t & 31) * 32, (t >> 5) * 32,
                       0, 1.0f, tile);
    }
}

// ---------------- shared-memory union for the mega kernel ----------------
struct AttnSM {
    u16 Ks[2][64 * 64];      // XOR-chunk-swizzled K tiles (double buffer)
    u16 Vt[64 * 72];         // Vt[d][j], row pad +8
    u16 ps[4][16 * 72];      // per-wave P tile, row pad +8
};                            // 34816 B

union MegaSM {
    struct { u16 As[2][256 * 64]; u16 Bs[2][192 * 64]; } g1;   // gemm1 staging: 114688 B
    u16 cs[256 * 200];                                         // gemm1 epilogue: 102400 B
    AttnSM at[2];                                              // 2 attn units:   69632 B
    struct { u16 As[2][128 * 64]; u16 Bs[2][128 * 64]; } g2;   // gemm2 staging:  65536 B
};

// ---------------- attention unit (one head-batch-qchunk, 256 threads) ----------------
// Same verified body as the standalone attn_kernel; LDS via AttnSM*. All internal
// __syncthreads are block-wide (512 thr) - the two concurrent units share qc, so
// trip counts are identical across halves.
__device__ __forceinline__ void attn_unit(const u16* __restrict__ qkv, u16* __restrict__ out,
                                          int b, int h, int qc, int t256, AttnSM* S) {
    const int wave = t256 >> 6, lane = t256 & 63;
    const int quad = lane >> 4, c16 = lane & 15;
    const int q0 = qc * 64;
    const int qw0 = q0 + wave * 16;

    frag_ab qf[2];
    {
        const u16* qrow = qkv + (size_t)(b * SEQ + qw0 + c16) * 3072 + h * 64;
        qf[0] = *(const frag_ab*)(qrow + quad * 8);
        qf[1] = *(const frag_ab*)(qrow + 32 + quad * 8);
    }

    float m_r[4], l_r[4];
    frag_cd acc[4] = {};

    const int ntiles = qc < 4 ? qc + 1 : 5;

    const int krow = wave * 16 + (lane >> 3);
    const int kchunk = (lane & 7) ^ (lane >> 3);
    const int vj2 = (t256 & 31) * 2, vd8 = t256 >> 5;

    const u16* kbase = qkv + (size_t)(b * SEQ + krow) * 3072 + 1024 + h * 64 + kchunk * 8;
    const u16* vbase = qkv + (size_t)(b * SEQ + vj2) * 3072 + 2048 + h * 64 + vd8 * 8;

    u16x8 va, vb;
    {
        const u16* g = kbase + (size_t)q0 * 3072;
        load_lds16(g,            &S->Ks[0][krow * 64 + (lane & 7) * 8]);
        load_lds16(g + 8 * 3072, &S->Ks[0][(krow + 8) * 64 + (lane & 7) * 8]);
        const u16* gv = vbase + (size_t)q0 * 3072;
        va = *(const u16x8*)gv;
        vb = *(const u16x8*)(gv + 3072);
#pragma unroll
        for (int dd = 0; dd < 8; dd++)
            *(u32*)&S->Vt[(vd8 * 8 + dd) * 72 + vj2] = (u32)va[dd] | ((u32)vb[dd] << 16);
    }

    for (int t = 0; t < ntiles; t++) {
        const int cur = t & 1, nxt = cur ^ 1;
        const int j0 = q0 - 64 * t;
        __syncthreads();                 // Ks[cur] + Vt staged & visible (block-wide)
        const bool pre = (t + 1 < ntiles);
        if (pre) {                       // prefetch t+1: K -> LDS[nxt] (async), V -> regs
            const u16* g = kbase + (size_t)(j0 - 64) * 3072;
            load_lds16(g,            &S->Ks[nxt][krow * 64 + (lane & 7) * 8]);
            load_lds16(g + 8 * 3072, &S->Ks[nxt][(krow + 8) * 64 + (lane & 7) * 8]);
            const u16* gv = vbase + (size_t)(j0 - 64) * 3072;
            va = *(const u16x8*)gv;
            vb = *(const u16x8*)(gv + 3072);
        }

        frag_cd s[4] = {};
#pragma unroll
        for (int kb = 0; kb < 4; kb++) {
            frag_ab kf0 = *(const frag_ab*)&S->Ks[cur][(kb * 16 + c16) * 64 + ((quad    ) ^ (c16 & 7)) * 8];
            frag_ab kf1 = *(const frag_ab*)&S->Ks[cur][(kb * 16 + c16) * 64 + ((4 + quad) ^ (c16 & 7)) * 8];
            s[kb] = __builtin_amdgcn_mfma_f32_16x16x32_bf16(qf[0], kf0, s[kb], 0, 0, 0);
            s[kb] = __builtin_amdgcn_mfma_f32_16x16x32_bf16(qf[1], kf1, s[kb], 0, 0, 0);
        }

        if (t == 0) {
#pragma unroll
            for (int reg = 0; reg < 4; reg++) {
                const int i = qw0 + quad * 4 + reg;
#pragma unroll
                for (int kb = 0; kb < 4; kb++)
                    if (q0 + kb * 16 + c16 > i) s[kb][reg] = -1e30f;
            }
        } else if (t == 4) {
#pragma unroll
            for (int reg = 0; reg < 4; reg++) {
                const int i = qw0 + quad * 4 + reg;
#pragma unroll
                for (int kb = 0; kb < 4; kb++)
                    if (j0 + kb * 16 + c16 + WIN <= i) s[kb][reg] = -1e30f;
            }
        }

        float mt_[4];
#pragma unroll
        for (int reg = 0; reg < 4; reg++)
            mt_[reg] = fmaxf(fmaxf(s[0][reg], s[1][reg]), fmaxf(s[2][reg], s[3][reg]));
#pragma unroll
        for (int off = 1; off < 16; off <<= 1)
#pragma unroll
            for (int reg = 0; reg < 4; reg++) mt_[reg] = fmaxf(mt_[reg], __shfl_xor(mt_[reg], off));

        float alpha[4];
        if (t == 0) {
#pragma unroll
            for (int reg = 0; reg < 4; reg++) m_r[reg] = mt_[reg];
        } else {
#pragma unroll
            for (int reg = 0; reg < 4; reg++) {
                float mn = fmaxf(m_r[reg], mt_[reg]);
                alpha[reg] = __builtin_amdgcn_exp2f(m_r[reg] - mn);
                m_r[reg] = mn;
            }
        }

        float rs[4] = {0.f, 0.f, 0.f, 0.f};
#pragma unroll
        for (int kb = 0; kb < 4; kb++)
#pragma unroll
            for (int reg = 0; reg < 4; reg++) {
                float p = __builtin_amdgcn_exp2f(s[kb][reg] - m_r[reg]);
                union { float f; u32 u; } pu; pu.f = p;
                S->ps[wave][(quad * 4 + reg) * 72 + kb * 16 + c16] = (u16)(pu.u >> 16);  // RTZ
                rs[reg] += p;
            }
#pragma unroll
        for (int off = 1; off < 16; off <<= 1)
#pragma unroll
            for (int reg = 0; reg < 4; reg++) rs[reg] += __shfl_xor(rs[reg], off);

        if (t == 0) {
#pragma unroll
            for (int reg = 0; reg < 4; reg++) l_r[reg] = rs[reg];
        } else {
#pragma unroll
            for (int reg = 0; reg < 4; reg++) l_r[reg] = l_r[reg] * alpha[reg] + rs[reg];
#pragma unroll
            for (int dblk = 0; dblk < 4; dblk++)
#pragma unroll
                for (int reg = 0; reg < 4; reg++) acc[dblk][reg] *= alpha[reg];
        }

#pragma unroll
        for (int js = 0; js < 2; js++) {
            frag_ab pf = *(const frag_ab*)&S->ps[wave][c16 * 72 + js * 32 + quad * 8];
#pragma unroll
            for (int dblk = 0; dblk < 4; dblk++) {
                frag_ab vf = *(const frag_ab*)&S->Vt[(dblk * 16 + c16) * 72 + js * 32 + quad * 8];
                acc[dblk] = __builtin_amdgcn_mfma_f32_16x16x32_bf16(pf, vf, acc[dblk], 0, 0, 0);
            }
        }

        if (pre) {
            __syncthreads();             // all waves done with PV(t) -> Vt overwrite safe
#pragma unroll
            for (int dd = 0; dd < 8; dd++)
                *(u32*)&S->Vt[(vd8 * 8 + dd) * 72 + vj2] = (u32)va[dd] | ((u32)vb[dd] << 16);
        }
    }

    float inv[4];
#pragma unroll
    for (int reg = 0; reg < 4; reg++) inv[reg] = 1.f / l_r[reg];
#pragma unroll
    for (int dblk = 0; dblk < 4; dblk++)
#pragma unroll
        for (int reg = 0; reg < 4; reg++)
            out[(size_t)(b * SEQ + qw0 + quad * 4 + reg) * 1024 + h * 64 + dblk * 16 + c16] =
                f2bf(acc[dblk][reg] * inv[reg]);
}

// ---------------- mega kernel: gemm1 -> gridsync -> attn -> gridsync -> gemm2 ----------------
// 256 blocks x 512 threads, 112 KB LDS -> exactly 1 block/CU, all co-resident.
// Stage 1 (gemm1): 256x192 tile, 8 waves (4Mx2N), fine-phased pipeline, counted vmcnt(7).
// Stage 2 (attn): 2 concurrent 256-thr units (same qc -> same trip count) x 2 rounds.
//   bh = (b&7) + 8*((b>>3)&1) + 16*half, qc = (b>>4)*2 + round -> head%8 == b&7 == XCD,
//   per-XCD KV working set 2 MB (L2-resident), same locality as the standalone kernel.
// Stage 3 (gemm2): 128x128 tile, 8 waves (2Mx4N), same pipeline family, counted vmcnt(4).
__global__ __launch_bounds__(512, 2) void mega_kernel(const u16* __restrict__ xb,
                                                      const u16* __restrict__ wqkvT,
                                                      u16* __restrict__ qkvb,
                                                      u16* __restrict__ attnb,
                                                      const u16* __restrict__ woutT,
                                                      float* __restrict__ out,
                                                      u32* __restrict__ sync_cnt) {
    __shared__ MegaSM sm;
    const int tid = threadIdx.x;
    const int bid = blockIdx.x;
    const int wave = tid >> 6, lane = tid & 63;
    const int l32 = lane & 31, kh = lane >> 5;

    // ================= stage 1: gemm1 (qkv = xb @ wqkvT^T) =================
    {
        constexpr int K = 1024, NLD = 3072, NT = K >> 6;   // 16 K-tiles
        const int xcd = bid & 7, sblk = bid >> 3;
        const int m0 = (sblk & 15) * 256;
        const int n0 = (xcd * 2 + (sblk >> 4)) * 192;
        const int wm = (wave >> 1) * 64, wn = (wave & 1) * 96;

        const int r0 = tid >> 3;                   // 0..63
        const int w  = (tid & 7) ^ (r0 & 7);       // swizzled source chunk
        const u16* aP = xb    + (size_t)(m0 + r0) * K + w * 8;
        const u16* bP = wqkvT + (size_t)(n0 + r0) * K + w * 8;

        f32x16 acc[2][3] = {};

#define STAGE1(tile_, buf_) do {                                                  \
        const int k0_ = (tile_) * 64;                                             \
        _Pragma("unroll")                                                         \
        for (int u = 0; u < 4; ++u)                                               \
            load_lds16(aP + (size_t)(64 * u) * K + k0_,                           \
                       &sm.g1.As[buf_][(tid + 512 * u) * 8]);                     \
        _Pragma("unroll")                                                         \
        for (int u = 0; u < 3; ++u)                                               \
            load_lds16(bP + (size_t)(64 * u) * K + k0_,                           \
                       &sm.g1.Bs[buf_][(tid + 512 * u) * 8]);                     \
    } while (0)

        STAGE1(0, 0);
        STAGE1(1, 1);

        int cur = 0;
        for (int t = 0; t < NT; ++t) {
            if (t + 1 < NT) asm volatile("s_waitcnt vmcnt(7)" ::: "memory");
            else            asm volatile("s_waitcnt vmcnt(0)" ::: "memory");
            asm volatile("s_barrier" ::: "memory");

            const u16* As = sm.g1.As[cur];
            const u16* Bs = sm.g1.Bs[cur];
#pragma unroll
            for (int kk = 0; kk < 4; ++kk) {
                const int csel = ((kk * 2 + kh) ^ (l32 & 7)) * 8;
                frag_ab af[2], bf[3];
#pragma unroll
                for (int mt = 0; mt < 2; ++mt)
                    af[mt] = *(const frag_ab*)&As[(wm + mt * 32 + l32) * 64 + csel];
#pragma unroll
                for (int nt = 0; nt < 3; ++nt)
                    bf[nt] = *(const frag_ab*)&Bs[(wn + nt * 32 + l32) * 64 + csel];
                asm volatile("s_barrier" ::: "memory");
                __builtin_amdgcn_s_setprio(1);
#pragma unroll
                for (int mt = 0; mt < 2; ++mt)
#pragma unroll
                    for (int nt = 0; nt < 3; ++nt)
                        acc[mt][nt] = __builtin_amdgcn_mfma_f32_32x32x16_bf16(
                            af[mt], bf[nt], acc[mt][nt], 0, 0, 0);
                __builtin_amdgcn_s_setprio(0);
                asm volatile("s_barrier" ::: "memory");
            }
            if (t + 2 < NT) STAGE1(t + 2, cur);
            cur ^= 1;
        }
#undef STAGE1

        // epilogue: acc -> LDS transpose, vectorized bf16 store to qkvb
#pragma unroll
        for (int mt = 0; mt < 2; ++mt)
#pragma unroll
            for (int nt = 0; nt < 3; ++nt) {
                const int col = wn + nt * 32 + l32;
#pragma unroll
                for (int reg = 0; reg < 16; ++reg) {
                    const int row = wm + mt * 32 + (reg & 3) + 8 * (reg >> 2) + 4 * kh;
                    sm.cs[row * 200 + col] = f2bf(acc[mt][nt][reg]);
                }
            }
        asm volatile("s_barrier" ::: "memory");
#pragma unroll
        for (int i = 0; i < 12; ++i) {
            const int idx = tid + 512 * i;          // 256 rows x 24 chunks
            const int row = idx / 24, c8 = idx % 24;
            u16x8 vv = *(const u16x8*)&sm.cs[row * 200 + c8 * 8];
            *(u16x8*)(qkvb + (size_t)(m0 + row) * NLD + n0 + c8 * 8) = vv;
        }
    }

    grid_sync(sync_cnt, 256);

    // ================= stage 2: attention =================
    {
        const int hh = tid >> 8, t256 = tid & 255;
        const int bh = (bid & 7) + 8 * ((bid >> 3) & 1) + 16 * hh;
        const int h = bh & 15, b = bh >> 4;
        const int qcbase = (bid >> 4) * 2;
#pragma unroll 1
        for (int r = 0; r < 2; ++r) {
            __syncthreads();             // prev round's LDS fully consumed
            attn_unit(qkvb, attnb, b, h, qcbase + r, t256, &sm.at[hh]);
        }
    }

    grid_sync(sync_cnt, 512);

    // ================= stage 3: gemm2 (out = attnb @ woutT^T) =================
    {
        constexpr int K = 1024, N = 1024, NT = K >> 6;
        const int xcd = bid & 7, sblk = bid >> 3;
        const int m0 = sblk * 128, n0 = xcd * 128;
        const int wm = (wave >> 2) * 64, wn = (wave & 3) * 32;

        const int r0 = tid >> 3;                   // 0..63
        const int w  = (tid & 7) ^ (r0 & 7);
        const u16* aP = attnb + (size_t)(m0 + r0) * K + w * 8;
        const u16* bP = woutT + (size_t)(n0 + r0) * K + w * 8;

        f32x16 acc[2] = {};

#define STAGE3(tile_, buf_) do {                                                  \
        const int k0_ = (tile_) * 64;                                             \
        _Pragma("unroll")                                                         \
        for (int u = 0; u < 2; ++u)                                               \
            load_lds16(aP + (size_t)(64 * u) * K + k0_,                           \
                       &sm.g2.As[buf_][(tid + 512 * u) * 8]);                     \
        _Pragma("unroll")                                                         \
        for (int u = 0; u < 2; ++u)                                               \
            load_lds16(bP + (size_t)(64 * u) * K + k0_,                           \
                       &sm.g2.Bs[buf_][(tid + 512 * u) * 8]);                     \
    } while (0)

        STAGE3(0, 0);
        STAGE3(1, 1);

        int cur = 0;
        for (int t = 0; t < NT; ++t) {
            if (t + 1 < NT) asm volatile("s_waitcnt vmcnt(4)" ::: "memory");
            else            asm volatile("s_waitcnt vmcnt(0)" ::: "memory");
            asm volatile("s_barrier" ::: "memory");

            const u16* As = sm.g2.As[cur];
            const u16* Bs = sm.g2.Bs[cur];
#pragma unroll
            for (int ph = 0; ph < 2; ++ph) {
                frag_ab af[2][2], bf[2];
#pragma unroll
                for (int kx = 0; kx < 2; ++kx) {
                    const int kk = ph * 2 + kx;
                    const int csel = ((kk * 2 + kh) ^ (l32 & 7)) * 8;
#pragma unroll
                    for (int mt = 0; mt < 2; ++mt)
                        af[kx][mt] = *(const frag_ab*)&As[(wm + mt * 32 + l32) * 64 + csel];
                    bf[kx] = *(const frag_ab*)&Bs[(wn + l32) * 64 + csel];
                }
                asm volatile("s_barrier" ::: "memory");
                __builtin_amdgcn_s_setprio(1);
#pragma unroll
                for (int kx = 0; kx < 2; ++kx)
#pragma unroll
                    for (int mt = 0; mt < 2; ++mt)
                        acc[mt] = __builtin_amdgcn_mfma_f32_32x32x16_bf16(
                            af[kx][mt], bf[kx], acc[mt], 0, 0, 0);
                __builtin_amdgcn_s_setprio(0);
                asm volatile("s_barrier" ::: "memory");
            }
            if (t + 2 < NT) STAGE3(t + 2, cur);
            cur ^= 1;
        }
#undef STAGE3

        // epilogue: direct f32 stores
#pragma unroll
        for (int mt = 0; mt < 2; ++mt) {
            const int col = n0 + wn + l32;
#pragma unroll
            for (int reg = 0; reg < 16; ++reg) {
                const int row = m0 + wm + mt * 32 + (reg & 3) + 8 * (reg >> 2) + 4 * kh;
                out[(size_t)row * N + col] = acc[mt][reg];
            }
        }
    }
}

extern "C" void kernel_launch(void* const* d_in, const int* in_sizes, int n_in,
                              void* d_out, int out_size, void* d_ws, size_t ws_size,
                              hipStream_t stream) {
    const float* x     = (const float*)d_in[0];   // [2,2048,1024]
    const float* W_qkv = (const float*)d_in[1];   // [1024,3072]
    const float* W_out = (const float*)d_in[2];   // [1024,1024]
    float* out = (float*)d_out;                   // [2,2048,1024]

    char* ws = (char*)d_ws;
    u16* xb    = (u16*)(ws);                       //  8 MB : x bf16 [4096,1024]
    u16* wqkvT = (u16*)(ws + 8388608);             //  6 MB : W_qkv^T bf16 [3072,1024] (q rows pre-scaled)
    u16* woutT = (u16*)(ws + 14680064);            //  2 MB : W_out^T bf16 [1024,1024]
    u16* qkvb  = (u16*)(ws + 16777216);            // 24 MB : qkv bf16 [4096,3072]
    u16* attnb = (u16*)(ws + 41943040);            //  8 MB : attn out bf16 [4096,1024]
    u32* scnt  = (u32*)(ws + 67108864);            // grid-sync counter (zeroed by prep)

    const float QSCALE = 0.125f * 1.4426950408889634f;  // 1/sqrt(64) * log2(e)

    prep_kernel<<<8192, 256, 0, stream>>>(x, W_qkv, W_out, xb, wqkvT, woutT, scnt, QSCALE);
    mega_kernel<<<256, 512, 0, stream>>>(xb, wqkvT, qkvb, attnb, woutT, out, scnt);
}

// Round 4
// 153.896 us; speedup vs baseline: 1.3316x; 1.3316x over previous
//
#include <hip/hip_runtime.h>

typedef unsigned short u16;
typedef unsigned int u32;

#define D_MODEL 1024
#define N_HEADS 16
#define D_HEAD 64
#define WIN 256
#define SEQ 2048
#define BATCH 2
#define NROWS (BATCH*SEQ)          // 4096 token rows

typedef short frag_ab __attribute__((ext_vector_type(8)));   // 8 bf16 (4 VGPRs)
typedef float frag_cd __attribute__((ext_vector_type(4)));   // 4 fp32 (16x16 C/D)
typedef float f32x16 __attribute__((ext_vector_type(16)));   // 32x32 C/D
typedef u16 u16x8 __attribute__((ext_vector_type(8)));

__device__ __forceinline__ u16 f2bf(float f) {
    union { float f; u32 u; } x; x.f = f;
    u32 r = x.u + 0x7fffu + ((x.u >> 16) & 1u);   // RNE
    return (u16)(r >> 16);
}

__device__ __forceinline__ void load_lds16(const void* g, void* l) {
    __builtin_amdgcn_global_load_lds(
        (const __attribute__((address_space(1))) void*)g,
        (__attribute__((address_space(3))) void*)l, 16, 0, 0);
}

// ---------------- transpose-cast tile helper (caller supplies LDS) ----------------
__device__ __forceinline__ void transpose_tile(const float* __restrict__ W, u16* __restrict__ WT,
                                               int K, int N, int n0, int k0,
                                               int scale_rows, float scale, float (*tile)[33]) {
    int x = threadIdx.x & 31, y = threadIdx.x >> 5;   // 32 x 8
#pragma unroll
    for (int r = 0; r < 4; r++)
        tile[y + 8 * r][x] = W[(size_t)(k0 + y + 8 * r) * N + n0 + x];
    __syncthreads();
#pragma unroll
    for (int r = 0; r < 4; r++) {
        int nrow = n0 + y + 8 * r;
        float v = tile[x][y + 8 * r];
        if (nrow < scale_rows) v *= scale;
        WT[(size_t)nrow * K + k0 + x] = f2bf(v);
    }
}

// ---------------- prep: cast x + transpose-cast W_qkv + W_out ----------------
__global__ __launch_bounds__(256) void prep_kernel(const float* __restrict__ x,
                                                   const float* __restrict__ W_qkv,
                                                   const float* __restrict__ W_out,
                                                   u16* __restrict__ xb,
                                                   u16* __restrict__ wqkvT,
                                                   u16* __restrict__ woutT,
                                                   float qscale) {
    __shared__ float tile[32][33];
    const int bid = blockIdx.x;
    if (bid < 4096) {
        int idx = bid * 256 + threadIdx.x;
        float4 v = ((const float4*)x)[idx];
        ushort4 o;
        o.x = f2bf(v.x); o.y = f2bf(v.y); o.z = f2bf(v.z); o.w = f2bf(v.w);
        ((ushort4*)xb)[idx] = o;
    } else if (bid < 7168) {
        int t = bid - 4096;                       // W_qkv: 96 x 32 tiles of 32x32
        transpose_tile(W_qkv, wqkvT, D_MODEL, 3 * D_MODEL, (t % 96) * 32, (t / 96) * 32,
                       D_MODEL, qscale, tile);
    } else {
        int t = bid - 7168;                       // W_out: 32 x 32 tiles
        transpose_tile(W_out, woutT, D_MODEL, D_MODEL, (t & 31) * 32, (t >> 5) * 32,
                       0, 1.0f, tile);
    }
}

// ---------------- bf16 GEMM: C[BM x 128] = A[M,K] * BT[N,K]^T, BK=64, 32x32x16 ----------------
// Proven m97-family structure (round-0 verified). 1D grid, XCD-aware decode
// (block%8 = XCD [m09]): xcd = B&7, s = B>>3, n_blk = xcd*NPER + s/MB, m_blk = s%MB.
// Staging: global_load_lds w/ XOR-chunk swizzle on the fetch side. Frag maps
// verified m74/m101: A/B lane m=lane&31, k=(lane>>5)*8+j;
// C/D col=lane&31, row=(reg&3)+8*(reg>>2)+4*(lane>>5).
template <bool BF16_OUT, int BM, int MB, int NPER>
__global__ __launch_bounds__(256, 4) void gemm_bk64(const u16* __restrict__ A,
                                                    const u16* __restrict__ BT,
                                                    void* __restrict__ C,
                                                    int M, int N, int K) {
    constexpr int MT = BM / 64;
    __shared__ union SMem {
        struct { u16 As[BM * 64]; u16 Bs[128 * 64]; } s;
        u16 cs[BF16_OUT ? BM * 136 : 1];          // epilogue transpose tile (bf16 path)
    } sm;
    const int tid = threadIdx.x;
    const int xcd = blockIdx.x & 7, sblk = blockIdx.x >> 3;
    const int m0 = (sblk % MB) * BM;
    const int n0 = (xcd * NPER + sblk / MB) * 128;
    const int wave = tid >> 6, lane = tid & 63;
    const int wm = (wave >> 1) * (BM / 2), wn = (wave & 1) * 64;
    const int l32 = lane & 31, kh = lane >> 5;

    f32x16 acc[MT][2] = {};

    const int r0 = tid >> 3;                   // 0..31
    const int w  = (tid & 7) ^ (r0 & 7);       // swizzled source chunk
    const u16* aP = A  + (size_t)(m0 + r0) * K + w * 8;
    const u16* bP = BT + (size_t)(n0 + r0) * K + w * 8;

    for (int k0 = 0; k0 < K; k0 += 64) {
        __syncthreads();
#pragma unroll
        for (int u = 0; u < BM / 32; u++)
            load_lds16(aP + (size_t)(32 * u) * K + k0, &sm.s.As[(tid + 256 * u) * 8]);
#pragma unroll
        for (int u = 0; u < 4; u++)
            load_lds16(bP + (size_t)(32 * u) * K + k0, &sm.s.Bs[(tid + 256 * u) * 8]);
        __syncthreads();

#pragma unroll
        for (int kk = 0; kk < 4; kk++) {
            const int csel = ((kk * 2 + kh) ^ (l32 & 7)) * 8;
            frag_ab af[MT], bf[2];
#pragma unroll
            for (int t = 0; t < MT; t++)
                af[t] = *(const frag_ab*)&sm.s.As[(wm + t * 32 + l32) * 64 + csel];
#pragma unroll
            for (int t = 0; t < 2; t++)
                bf[t] = *(const frag_ab*)&sm.s.Bs[(wn + t * 32 + l32) * 64 + csel];
#pragma unroll
            for (int mt = 0; mt < MT; mt++)
#pragma unroll
                for (int nt = 0; nt < 2; nt++)
                    acc[mt][nt] = __builtin_amdgcn_mfma_f32_32x32x16_bf16(af[mt], bf[nt], acc[mt][nt], 0, 0, 0);
        }
    }

    if constexpr (BF16_OUT) {
        __syncthreads();
#pragma unroll
        for (int mt = 0; mt < MT; mt++)
#pragma unroll
            for (int nt = 0; nt < 2; nt++) {
                int col = wn + nt * 32 + l32;
#pragma unroll
                for (int reg = 0; reg < 16; reg++) {
                    int row = wm + mt * 32 + (reg & 3) + 8 * (reg >> 2) + 4 * kh;
                    sm.cs[row * 136 + col] = f2bf(acc[mt][nt][reg]);
                }
            }
        __syncthreads();
        const int cc = tid & 15, rb = tid >> 4;
#pragma unroll
        for (int i = 0; i < BM / 16; i++) {
            int row = rb + 16 * i;
            u16x8 vv = *(const u16x8*)&sm.cs[row * 136 + cc * 8];
            *(u16x8*)((u16*)C + (size_t)(m0 + row) * N + n0 + cc * 8) = vv;
        }
    } else {
#pragma unroll
        for (int mt = 0; mt < MT; mt++)
#pragma unroll
            for (int nt = 0; nt < 2; nt++) {
                int col = n0 + wn + nt * 32 + l32;
#pragma unroll
                for (int reg = 0; reg < 16; reg++) {
                    int row = m0 + wm + mt * 32 + (reg & 3) + 8 * (reg >> 2) + 4 * kh;
                    ((float*)C)[(size_t)row * N + col] = acc[mt][nt][reg];
                }
            }
    }
}

// ---------------- MFMA flash attention (sliding window), pipelined ----------------
// 1024 blocks: decode head=B&31, qc=B>>5 -> all 32 q-tiles of a head land on
// XCD head%8; per-XCD KV working set = 4 heads x 512 KB = 2 MB, L2-resident
// across the ~5x KV re-read.
__global__ __launch_bounds__(256) void attn_kernel(const u16* __restrict__ qkv,
                                                   u16* __restrict__ out) {
    __shared__ u16 Ks[2][64 * 64];       // XOR-chunk-swizzled: chunk c of row r at c^(r&7)
    __shared__ u16 Vt[64 * 72];          // Vt[d][j], row pad +8 (single buffer)
    __shared__ u16 ps[4][16 * 72];       // per-wave P tile, row pad +8

    const int tid = threadIdx.x;
    const int wave = tid >> 6, lane = tid & 63;
    const int quad = lane >> 4, c16 = lane & 15;

    const int bh = blockIdx.x & 31;      // b*16+h  -> XCD = bh%8
    const int qc = blockIdx.x >> 5;      // 0..31
    const int h  = bh & 15;
    const int b  = bh >> 4;
    const int q0 = qc * 64;
    const int qw0 = q0 + wave * 16;

    frag_ab qf[2];
    {
        const u16* qrow = qkv + (size_t)(b * SEQ + qw0 + c16) * 3072 + h * 64;
        qf[0] = *(const frag_ab*)(qrow + quad * 8);
        qf[1] = *(const frag_ab*)(qrow + 32 + quad * 8);
    }

    float m_r[4], l_r[4];
    frag_cd acc[4] = {};

    const int ntiles = qc < 4 ? qc + 1 : 5;

    const int krow = wave * 16 + (lane >> 3);
    const int kchunk = (lane & 7) ^ (lane >> 3);
    const int vj2 = (tid & 31) * 2, vd8 = tid >> 5;

    const u16* kbase = qkv + (size_t)(b * SEQ + krow) * 3072 + 1024 + h * 64 + kchunk * 8;
    const u16* vbase = qkv + (size_t)(b * SEQ + vj2) * 3072 + 2048 + h * 64 + vd8 * 8;

    u16x8 va, vb;
    {
        const u16* g = kbase + (size_t)q0 * 3072;
        load_lds16(g,            &Ks[0][krow * 64 + (lane & 7) * 8]);
        load_lds16(g + 8 * 3072, &Ks[0][(krow + 8) * 64 + (lane & 7) * 8]);
        const u16* gv = vbase + (size_t)q0 * 3072;
        va = *(const u16x8*)gv;
        vb = *(const u16x8*)(gv + 3072);
#pragma unroll
        for (int dd = 0; dd < 8; dd++)
            *(u32*)&Vt[(vd8 * 8 + dd) * 72 + vj2] = (u32)va[dd] | ((u32)vb[dd] << 16);
    }

    for (int t = 0; t < ntiles; t++) {
        const int cur = t & 1, nxt = cur ^ 1;
        const int j0 = q0 - 64 * t;
        __syncthreads();                 // Ks[cur] + Vt staged & visible
        const bool pre = (t + 1 < ntiles);
        if (pre) {                       // prefetch t+1: K -> LDS[nxt] (async), V -> regs
            const u16* g = kbase + (size_t)(j0 - 64) * 3072;
            load_lds16(g,            &Ks[nxt][krow * 64 + (lane & 7) * 8]);
            load_lds16(g + 8 * 3072, &Ks[nxt][(krow + 8) * 64 + (lane & 7) * 8]);
            const u16* gv = vbase + (size_t)(j0 - 64) * 3072;
            va = *(const u16x8*)gv;
            vb = *(const u16x8*)(gv + 3072);
        }

        frag_cd s[4] = {};
#pragma unroll
        for (int kb = 0; kb < 4; kb++) {
            frag_ab kf0 = *(const frag_ab*)&Ks[cur][(kb * 16 + c16) * 64 + ((quad    ) ^ (c16 & 7)) * 8];
            frag_ab kf1 = *(const frag_ab*)&Ks[cur][(kb * 16 + c16) * 64 + ((4 + quad) ^ (c16 & 7)) * 8];
            s[kb] = __builtin_amdgcn_mfma_f32_16x16x32_bf16(qf[0], kf0, s[kb], 0, 0, 0);
            s[kb] = __builtin_amdgcn_mfma_f32_16x16x32_bf16(qf[1], kf1, s[kb], 0, 0, 0);
        }

        if (t == 0) {
#pragma unroll
            for (int reg = 0; reg < 4; reg++) {
                const int i = qw0 + quad * 4 + reg;
#pragma unroll
                for (int kb = 0; kb < 4; kb++)
                    if (q0 + kb * 16 + c16 > i) s[kb][reg] = -1e30f;
            }
        } else if (t == 4) {
#pragma unroll
            for (int reg = 0; reg < 4; reg++) {
                const int i = qw0 + quad * 4 + reg;
#pragma unroll
                for (int kb = 0; kb < 4; kb++)
                    if (j0 + kb * 16 + c16 + WIN <= i) s[kb][reg] = -1e30f;
            }
        }

        float mt_[4];
#pragma unroll
        for (int reg = 0; reg < 4; reg++)
            mt_[reg] = fmaxf(fmaxf(s[0][reg], s[1][reg]), fmaxf(s[2][reg], s[3][reg]));
#pragma unroll
        for (int off = 1; off < 16; off <<= 1)
#pragma unroll
            for (int reg = 0; reg < 4; reg++) mt_[reg] = fmaxf(mt_[reg], __shfl_xor(mt_[reg], off));

        float alpha[4];
        if (t == 0) {
#pragma unroll
            for (int reg = 0; reg < 4; reg++) m_r[reg] = mt_[reg];
        } else {
#pragma unroll
            for (int reg = 0; reg < 4; reg++) {
                float mn = fmaxf(m_r[reg], mt_[reg]);
                alpha[reg] = __builtin_amdgcn_exp2f(m_r[reg] - mn);
                m_r[reg] = mn;
            }
        }

        float rs[4] = {0.f, 0.f, 0.f, 0.f};
#pragma unroll
        for (int kb = 0; kb < 4; kb++)
#pragma unroll
            for (int reg = 0; reg < 4; reg++) {
                float p = __builtin_amdgcn_exp2f(s[kb][reg] - m_r[reg]);
                union { float f; u32 u; } pu; pu.f = p;
                ps[wave][(quad * 4 + reg) * 72 + kb * 16 + c16] = (u16)(pu.u >> 16);  // RTZ
                rs[reg] += p;
            }
#pragma unroll
        for (int off = 1; off < 16; off <<= 1)
#pragma unroll
            for (int reg = 0; reg < 4; reg++) rs[reg] += __shfl_xor(rs[reg], off);

        if (t == 0) {
#pragma unroll
            for (int reg = 0; reg < 4; reg++) l_r[reg] = rs[reg];
        } else {
#pragma unroll
            for (int reg = 0; reg < 4; reg++) l_r[reg] = l_r[reg] * alpha[reg] + rs[reg];
#pragma unroll
            for (int dblk = 0; dblk < 4; dblk++)
#pragma unroll
                for (int reg = 0; reg < 4; reg++) acc[dblk][reg] *= alpha[reg];
        }

#pragma unroll
        for (int js = 0; js < 2; js++) {
            frag_ab pf = *(const frag_ab*)&ps[wave][c16 * 72 + js * 32 + quad * 8];
#pragma unroll
            for (int dblk = 0; dblk < 4; dblk++) {
                frag_ab vf = *(const frag_ab*)&Vt[(dblk * 16 + c16) * 72 + js * 32 + quad * 8];
                acc[dblk] = __builtin_amdgcn_mfma_f32_16x16x32_bf16(pf, vf, acc[dblk], 0, 0, 0);
            }
        }

        if (pre) {
            __syncthreads();             // all waves done with PV(t) -> Vt overwrite safe
#pragma unroll
            for (int dd = 0; dd < 8; dd++)
                *(u32*)&Vt[(vd8 * 8 + dd) * 72 + vj2] = (u32)va[dd] | ((u32)vb[dd] << 16);
        }
    }

    float inv[4];
#pragma unroll
    for (int reg = 0; reg < 4; reg++) inv[reg] = 1.f / l_r[reg];
#pragma unroll
    for (int dblk = 0; dblk < 4; dblk++)
#pragma unroll
        for (int reg = 0; reg < 4; reg++)
            out[(size_t)(b * SEQ + qw0 + quad * 4 + reg) * 1024 + h * 64 + dblk * 16 + c16] =
                f2bf(acc[dblk][reg] * inv[reg]);
}

extern "C" void kernel_launch(void* const* d_in, const int* in_sizes, int n_in,
                              void* d_out, int out_size, void* d_ws, size_t ws_size,
                              hipStream_t stream) {
    const float* x     = (const float*)d_in[0];   // [2,2048,1024]
    const float* W_qkv = (const float*)d_in[1];   // [1024,3072]
    const float* W_out = (const float*)d_in[2];   // [1024,1024]
    float* out = (float*)d_out;                   // [2,2048,1024]

    char* ws = (char*)d_ws;
    u16* xb    = (u16*)(ws);                       //  8 MB : x bf16 [4096,1024]
    u16* wqkvT = (u16*)(ws + 8388608);             //  6 MB : W_qkv^T bf16 [3072,1024] (q rows pre-scaled)
    u16* woutT = (u16*)(ws + 14680064);            //  2 MB : W_out^T bf16 [1024,1024]
    u16* qkvb  = (u16*)(ws + 16777216);            // 24 MB : qkv bf16 [4096,3072]
    u16* attnb = (u16*)(ws + 41943040);            //  8 MB : attn out bf16 [4096,1024]

    const float QSCALE = 0.125f * 1.4426950408889634f;  // 1/sqrt(64) * log2(e)

    // prep: x cast (4096) + W_qkv transpose (3072) + W_out transpose (1024)
    prep_kernel<<<8192, 256, 0, stream>>>(x, W_qkv, W_out, xb, wqkvT, woutT, QSCALE);
    // gemm1: qkv = xb @ wqkvT^T. 768 blocks, XCD-swizzled (3 n-blocks per XCD). [round-0 proven]
    gemm_bk64<true, 128, 32, 3><<<768, 256, 0, stream>>>(
        xb, wqkvT, qkvb, NROWS, 3 * D_MODEL, D_MODEL);
    // attn: 1024 blocks, head-per-XCD swizzle (transpose work moved to prep)
    attn_kernel<<<1024, 256, 0, stream>>>(qkvb, attnb);
    // gemm2: out = attnb @ woutT^T. 256 blocks, BM=128 (was BM=64): doubled
    // MFMA-per-staging-byte, same proven template. 8 XCD x 32 m-blocks.
    gemm_bk64<false, 128, 32, 1><<<256, 256, 0, stream>>>(
        attnb, woutT, out, NROWS, D_MODEL, D_MODEL);
}